// Round 8
// baseline (164.838 us; speedup 1.0000x reference)
//
#include <hip/hip_runtime.h>
#include <hip/hip_cooperative_groups.h>
#include <math.h>

namespace cg = cooperative_groups;

#define LOG2E 1.44269504088896340736f
typedef float v2f __attribute__((ext_vector_type(2)));

// ws layout:
//   ctx   [32][2][768]  : scene_context | speaker_context
//   final [32][3840]    : [z(2304) | sent_sh(512) | scene_sh(512) | spkr_sh(512)]
//   hpart [32][16][256] : mlp stage-1 K-split partials
//
// Single cooperative kernel, 512 threads/block, 4 phases separated by grid.sync():
//   P1: 384 small-attn items (b x part x rowgroup128) + 32 sentence-proj items
//   P2: 576 fused-attn items (b x rowgroup128) + 64 ctx-proj items
//   P3: 512 mlp stage-1 items (b x 16 K-chunks of 240)
//   P4: 32 mlp tail items (b)

__device__ __forceinline__ void proj_768x512(
    const float* __restrict__ xsrc,          // [768]
    const float* __restrict__ Ws,            // [768, 512]
    const float* __restrict__ bs,            // [512]
    float* __restrict__ dst,                 // [512]
    float* xb,                               // LDS [768]
    float* redf,                             // LDS [4][512]
    int tid)
{
    if (tid < 512) { xb[tid] = xsrc[tid]; }
    if (tid >= 256) { xb[tid + 256] = xsrc[tid + 256]; }
    __syncthreads();

    const int g = tid >> 7;        // 0..3
    const int q = tid & 127;       // column quad
    const float4* __restrict__ Wv = (const float4*)Ws;   // [768][128]
    float ax = 0.f, ay = 0.f, az = 0.f, aw = 0.f;
    #pragma unroll 8
    for (int k = g; k < 768; k += 4) {
        const float xv = xb[k];
        const float4 w = Wv[k * 128 + q];
        ax += xv * w.x; ay += xv * w.y; az += xv * w.z; aw += xv * w.w;
    }
    redf[g * 512 + q * 4 + 0] = ax;
    redf[g * 512 + q * 4 + 1] = ay;
    redf[g * 512 + q * 4 + 2] = az;
    redf[g * 512 + q * 4 + 3] = aw;
    __syncthreads();

    if (tid < 512) {
        dst[tid] = bs[tid] + redf[0 * 512 + tid] + redf[1 * 512 + tid]
                           + redf[2 * 512 + tid] + redf[3 * 512 + tid];
    }
}

// attn over 128 rows (r0-base) with K/V staged in LDS; 8 subs/row, 2 rows/thread.
__device__ __forceinline__ void attn128(
    const float* __restrict__ qsrc,   // [>= r0+128] q values (global or LDS base semantics)
    const float4* __restrict__ kv,    // LDS, n4 float4 of k
    const float4* __restrict__ vv,    // LDS, n4 float4 of v (may equal kv)
    int n4,                           // 192 or 576
    int r0base, int tid,
    float* __restrict__ out0,         // write out0[r], out0[r+64]
    int outstride_r0)
{
    const int r0  = r0base + (tid >> 3);
    const int r1  = r0 + 64;
    const int sub = tid & 7;
    const float qA = qsrc[r0] * LOG2E;
    const float qB = qsrc[r1] * LOG2E;
    const v2f qA2 = {qA, qA}, qB2 = {qB, qB};
    v2f nA0 = {0.f,0.f}, nA1 = {0.f,0.f}, dA0 = {0.f,0.f}, dA1 = {0.f,0.f};
    v2f nB0 = {0.f,0.f}, nB1 = {0.f,0.f}, dB0 = {0.f,0.f}, dB1 = {0.f,0.f};
    #pragma unroll 4
    for (int j = sub; j < n4; j += 8) {
        const float4 k4 = kv[j];
        const float4 v4 = vv[j];
        const v2f ka = {k4.x, k4.y}, kb = {k4.z, k4.w};
        const v2f va = {v4.x, v4.y}, vb2 = {v4.z, v4.w};
        const v2f xaA = qA2 * ka, xbA = qA2 * kb;
        const v2f eaA = {__builtin_amdgcn_exp2f(xaA.x), __builtin_amdgcn_exp2f(xaA.y)};
        const v2f ebA = {__builtin_amdgcn_exp2f(xbA.x), __builtin_amdgcn_exp2f(xbA.y)};
        nA0 += eaA * va;  dA0 += eaA;
        nA1 += ebA * vb2; dA1 += ebA;
        const v2f xaB = qB2 * ka, xbB = qB2 * kb;
        const v2f eaB = {__builtin_amdgcn_exp2f(xaB.x), __builtin_amdgcn_exp2f(xaB.y)};
        const v2f ebB = {__builtin_amdgcn_exp2f(xbB.x), __builtin_amdgcn_exp2f(xbB.y)};
        nB0 += eaB * va;  dB0 += eaB;
        nB1 += ebB * vb2; dB1 += ebB;
    }
    float numA = (nA0.x + nA0.y) + (nA1.x + nA1.y);
    float denA = (dA0.x + dA0.y) + (dA1.x + dA1.y);
    float numB = (nB0.x + nB0.y) + (nB1.x + nB1.y);
    float denB = (dB0.x + dB0.y) + (dB1.x + dB1.y);
    numA += __shfl_xor(numA, 1, 64); numA += __shfl_xor(numA, 2, 64); numA += __shfl_xor(numA, 4, 64);
    denA += __shfl_xor(denA, 1, 64); denA += __shfl_xor(denA, 2, 64); denA += __shfl_xor(denA, 4, 64);
    numB += __shfl_xor(numB, 1, 64); numB += __shfl_xor(numB, 2, 64); numB += __shfl_xor(numB, 4, 64);
    denB += __shfl_xor(denB, 1, 64); denB += __shfl_xor(denB, 2, 64); denB += __shfl_xor(denB, 4, 64);
    if (sub == 0) {
        out0[outstride_r0 + r0 - r0base] = numA / denA;
        out0[outstride_r0 + r1 - r0base] = numB / denB;
    }
}

__global__ __launch_bounds__(512) void mega_kernel(
    const float* __restrict__ sentence,
    const float* __restrict__ target,
    const float* __restrict__ other,
    const float* __restrict__ scene_desc,
    const float* __restrict__ scene_sent,
    const float* __restrict__ Ws,
    const float* __restrict__ bs,
    const float* __restrict__ W1,
    const float* __restrict__ b1,
    const float* __restrict__ W2,
    const float* __restrict__ b2,
    float* __restrict__ out,
    float* __restrict__ ctx,
    float* __restrict__ final_,
    float* __restrict__ hpart)
{
    cg::grid_group grid = cg::this_grid();
    const int tid = threadIdx.x;
    __shared__ float smem[2304];     // staging: s0|s1 (p1), vb (p2), xb (proj), fb (p3), hb (p4)
    __shared__ float redf[2048];     // [4][512] (proj) or [8][256] (p3)

    // ---------------- Phase 1: small attns + sentence projection ----------------
    for (int item = blockIdx.x; item < 416; item += gridDim.x) {
        __syncthreads();
        if (item < 384) {
            const int b    = item / 12;
            const int rem  = item - b * 12;
            const int part = rem / 6;      // 0: scene ctx, 1: speaker ctx
            const int rg   = rem - part * 6;
            const float* qp; const float* kp; const float* vp;
            if (part == 0) { qp = scene_sent + b * 768; kp = qp;               vp = scene_desc + b * 768; }
            else           { qp = other + b * 768;      kp = target + b * 768; vp = kp; }
            for (int i = tid; i < 768; i += 512) { smem[i] = kp[i]; smem[768 + i] = vp[i]; }
            __syncthreads();
            attn128(qp, (const float4*)smem, (const float4*)(smem + 768), 192,
                    rg * 128, tid, ctx + b * 1536 + part * 768 + rg * 128, 0);
        } else {
            const int b = item - 384;
            proj_768x512(sentence + b * 768, Ws, bs, final_ + b * 3840 + 2304,
                         smem, redf, tid);
        }
    }
    grid.sync();

    // ---------------- Phase 2: fused attn + ctx projections ----------------
    for (int item = blockIdx.x; item < 640; item += gridDim.x) {
        __syncthreads();
        if (item < 576) {
            const int b = item / 18;
            const int y = item - b * 18;
            for (int i = tid; i < 2304; i += 512)
                smem[i] = (i < 768) ? sentence[b * 768 + i] : ctx[b * 1536 + (i - 768)];
            __syncthreads();
            attn128(smem, (const float4*)smem, (const float4*)smem, 576,
                    y * 128, tid, final_ + b * 3840 + y * 128, 0);
        } else {
            const int j = item - 576;      // 0..63
            const int b = j >> 1;
            const int p = 1 + (j & 1);
            proj_768x512(ctx + b * 1536 + (p - 1) * 768, Ws, bs,
                         final_ + b * 3840 + 2304 + p * 512, smem, redf, tid);
        }
    }
    grid.sync();

    // ---------------- Phase 3: MLP stage 1 (K-split partials) ----------------
    for (int item = blockIdx.x; item < 512; item += gridDim.x) {
        __syncthreads();
        const int b = item >> 4;
        const int c = item & 15;
        const int base = c * 240;
        if (tid < 240) smem[tid] = final_[b * 3840 + base + tid];
        __syncthreads();

        const int g = tid >> 6;        // wave id, 8 waves
        const int q = tid & 63;        // column quad
        const float4* __restrict__ Wv = (const float4*)W1;   // [3840][64]
        float ax = 0.f, ay = 0.f, az = 0.f, aw = 0.f;
        const int l0 = g * 30;
        #pragma unroll 5
        for (int kk = 0; kk < 30; ++kk) {
            const float xv = smem[l0 + kk];
            const float4 w = Wv[(base + l0 + kk) * 64 + q];
            ax += xv * w.x; ay += xv * w.y; az += xv * w.z; aw += xv * w.w;
        }
        redf[g * 256 + q * 4 + 0] = ax;
        redf[g * 256 + q * 4 + 1] = ay;
        redf[g * 256 + q * 4 + 2] = az;
        redf[g * 256 + q * 4 + 3] = aw;
        __syncthreads();

        if (tid < 256) {
            float s = 0.f;
            #pragma unroll
            for (int g2 = 0; g2 < 8; ++g2) s += redf[g2 * 256 + tid];
            hpart[(b * 16 + c) * 256 + tid] = s;
        }
    }
    grid.sync();

    // ---------------- Phase 4: MLP tail ----------------
    for (int item = blockIdx.x; item < 32; item += gridDim.x) {
        __syncthreads();
        const int b = item;
        if (tid < 256) {
            float s = b1[tid];
            #pragma unroll
            for (int c = 0; c < 16; ++c) s += hpart[(b * 16 + c) * 256 + tid];
            smem[tid] = fmaxf(s, 0.f);
        }
        __syncthreads();

        const int w = tid >> 6;
        const int lane = tid & 63;
        if (w < 7) {
            float a = 0.f;
            #pragma unroll
            for (int c = lane; c < 256; c += 64)
                a += smem[c] * W2[c * 7 + w];
            #pragma unroll
            for (int off = 32; off > 0; off >>= 1)
                a += __shfl_down(a, off, 64);
            if (lane == 0)
                out[b * 7 + w] = 1.f / (1.f + __expf(-(a + b2[w])));
        }
    }
}

extern "C" void kernel_launch(void* const* d_in, const int* in_sizes, int n_in,
                              void* d_out, int out_size, void* d_ws, size_t ws_size,
                              hipStream_t stream) {
    const float* sentence   = (const float*)d_in[0];
    const float* target     = (const float*)d_in[1];
    const float* other      = (const float*)d_in[2];
    const float* scene_desc = (const float*)d_in[3];
    const float* scene_sent = (const float*)d_in[4];
    const float* Ws         = (const float*)d_in[5];
    const float* bs         = (const float*)d_in[6];
    const float* W1         = (const float*)d_in[7];
    const float* b1         = (const float*)d_in[8];
    const float* W2         = (const float*)d_in[9];
    const float* b2         = (const float*)d_in[10];
    float* out = (float*)d_out;

    float* ctx    = (float*)d_ws;             // 32*1536 floats
    float* final_ = ctx + 32 * 1536;          // 32*3840 floats
    float* hpart  = final_ + 32 * 3840;       // 32*16*256 floats

    int nb = 0;
    (void)hipOccupancyMaxActiveBlocksPerMultiprocessor(&nb, mega_kernel, 512, 0);
    if (nb < 1) nb = 1;
    int gridSize = nb * 256;
    if (gridSize > 640) gridSize = 640;

    void* args[] = {
        (void*)&sentence, (void*)&target, (void*)&other, (void*)&scene_desc,
        (void*)&scene_sent, (void*)&Ws, (void*)&bs, (void*)&W1, (void*)&b1,
        (void*)&W2, (void*)&b2, (void*)&out, (void*)&ctx, (void*)&final_,
        (void*)&hpart
    };
    (void)hipLaunchCooperativeKernel((void*)mega_kernel, dim3(gridSize), dim3(512),
                                     args, 0, stream);
}

// Round 9
// 66.979 us; speedup vs baseline: 2.4610x; 2.4610x over previous
//
#include <hip/hip_runtime.h>
#include <math.h>

#define LOG2E 1.44269504088896340736f
typedef float v2f __attribute__((ext_vector_type(2)));

// ws layout:
//   ctx   [32][2][768]  : scene_context | speaker_context
//   final [32][3840]    : [z(2304) | sent_sh(512) | scene_sh(512) | spkr_sh(512)]
//   hpart [32][8][256]  : mlp stage-1 K-split partials

// ---- projection helper: [768] x [768,512] with 256 threads, 2-way K-split
__device__ __forceinline__ void proj_256(
    const float* __restrict__ xsrc,
    const float* __restrict__ Ws,            // [768, 512]
    const float* __restrict__ bs,            // [512]
    float* __restrict__ dst,
    float* xb,                               // LDS [768]
    float* redf,                             // LDS [1024] = [2][512]
    int tid)
{
    for (int i = tid; i < 768; i += 256) xb[i] = xsrc[i];
    __syncthreads();

    const int g = tid >> 7;        // 0..1
    const int q = tid & 127;       // column quad
    const float4* __restrict__ Wv = (const float4*)Ws;   // [768][128]
    float ax = 0.f, ay = 0.f, az = 0.f, aw = 0.f;
    #pragma unroll 8
    for (int k = g; k < 768; k += 2) {
        const float xv = xb[k];
        const float4 w = Wv[k * 128 + q];
        ax += xv * w.x; ay += xv * w.y; az += xv * w.z; aw += xv * w.w;
    }
    redf[g * 512 + q * 4 + 0] = ax;
    redf[g * 512 + q * 4 + 1] = ay;
    redf[g * 512 + q * 4 + 2] = az;
    redf[g * 512 + q * 4 + 3] = aw;
    __syncthreads();

    dst[tid]       = bs[tid]       + redf[tid]       + redf[512 + tid];
    dst[tid + 256] = bs[tid + 256] + redf[tid + 256] + redf[512 + tid + 256];
}

// ---- attention core: 256 threads, 16 subs/row, 4 rows/thread (64 rows/block).
// Rows i0+16m (m=0..3), i0 = rbase + (tid>>4). kv/vv: n4 float4s in LDS.
__device__ __forceinline__ void attn_r4(
    const float* __restrict__ qsrc,
    const float4* __restrict__ kv,
    const float4* __restrict__ vv,
    int n4, int rbase, int tid,
    float* __restrict__ outp)
{
    const int i0  = rbase + (tid >> 4);
    const int sub = tid & 15;
    v2f q2[4];
    #pragma unroll
    for (int m = 0; m < 4; ++m) {
        const float qL = qsrc[i0 + 16 * m] * LOG2E;
        q2[m] = (v2f){qL, qL};
    }
    v2f n0[4], n1[4], d0[4], d1[4];
    #pragma unroll
    for (int m = 0; m < 4; ++m) {
        n0[m] = (v2f){0.f, 0.f}; n1[m] = (v2f){0.f, 0.f};
        d0[m] = (v2f){0.f, 0.f}; d1[m] = (v2f){0.f, 0.f};
    }
    #pragma unroll 2
    for (int j = sub; j < n4; j += 16) {
        const float4 k4 = kv[j];
        const float4 v4 = vv[j];
        const v2f ka = {k4.x, k4.y}, kb = {k4.z, k4.w};
        const v2f va = {v4.x, v4.y}, vb2 = {v4.z, v4.w};
        #pragma unroll
        for (int m = 0; m < 4; ++m) {
            const v2f xa = q2[m] * ka, xb = q2[m] * kb;
            const v2f ea = {__builtin_amdgcn_exp2f(xa.x), __builtin_amdgcn_exp2f(xa.y)};
            const v2f eb = {__builtin_amdgcn_exp2f(xb.x), __builtin_amdgcn_exp2f(xb.y)};
            n0[m] += ea * va;  d0[m] += ea;
            n1[m] += eb * vb2; d1[m] += eb;
        }
    }
    #pragma unroll
    for (int m = 0; m < 4; ++m) {
        float num = (n0[m].x + n0[m].y) + (n1[m].x + n1[m].y);
        float den = (d0[m].x + d0[m].y) + (d1[m].x + d1[m].y);
        num += __shfl_xor(num, 1, 64); num += __shfl_xor(num, 2, 64);
        num += __shfl_xor(num, 4, 64); num += __shfl_xor(num, 8, 64);
        den += __shfl_xor(den, 1, 64); den += __shfl_xor(den, 2, 64);
        den += __shfl_xor(den, 4, 64); den += __shfl_xor(den, 8, 64);
        if (sub == 0) outp[i0 + 16 * m] = num / den;
    }
}

// K1: small attentions (y<24: 2 parts x 12 rowgroups of 64) + sentence proj (y=24).
// 256 threads.
__global__ __launch_bounds__(256) void k1_small_attn_proj0(
    const float* __restrict__ sentence,
    const float* __restrict__ target,
    const float* __restrict__ other,
    const float* __restrict__ scene_desc,
    const float* __restrict__ scene_sent,
    const float* __restrict__ Ws,
    const float* __restrict__ bs,
    float* __restrict__ ctx,
    float* __restrict__ final_)
{
    const int b = blockIdx.x;
    const int y = blockIdx.y;
    const int tid = threadIdx.x;
    __shared__ float s0[768];
    __shared__ float s1[768];
    __shared__ float redf[1024];

    if (y < 24) {
        const int part = y / 12;       // 0: scene ctx, 1: speaker ctx
        const int rg = y - part * 12;
        const float* qp; const float* kp; const float* vp;
        if (part == 0) { qp = scene_sent + b * 768; kp = qp;               vp = scene_desc + b * 768; }
        else           { qp = other + b * 768;      kp = target + b * 768; vp = kp; }
        for (int i = tid; i < 768; i += 256) { s0[i] = kp[i]; s1[i] = vp[i]; }
        __syncthreads();
        attn_r4(qp, (const float4*)s0, (const float4*)s1, 192,
                rg * 64, tid, ctx + b * 1536 + part * 768);
    } else {
        proj_256(sentence + b * 768, Ws, bs, final_ + b * 3840 + 2304, s0, redf, tid);
    }
}

// K2: fused self-attention over f=[sentence|ctx] (y<36: rowgroups of 64) +
// ctx projections (y=36,37). 256 threads.
__global__ __launch_bounds__(256) void k2_fused_attn_proj12(
    const float* __restrict__ sentence,
    const float* __restrict__ ctx,
    const float* __restrict__ Ws,
    const float* __restrict__ bs,
    float* __restrict__ final_)
{
    const int b = blockIdx.x;
    const int y = blockIdx.y;
    const int tid = threadIdx.x;
    __shared__ float vb[2304];
    __shared__ float redf[1024];

    if (y < 36) {
        for (int i = tid; i < 2304; i += 256)
            vb[i] = (i < 768) ? sentence[b * 768 + i] : ctx[b * 1536 + (i - 768)];
        __syncthreads();
        attn_r4(vb, (const float4*)vb, (const float4*)vb, 576,
                y * 64, tid, final_ + b * 3840);
    } else {
        const int p = y - 35;          // 1 or 2
        proj_256(ctx + b * 1536 + (p - 1) * 768, Ws, bs,
                 final_ + b * 3840 + 2304 + p * 512, vb, redf, tid);
    }
}

// MLP stage 1, K-split across blocks: grid (32,8), 1024 threads.
__global__ __launch_bounds__(1024) void mlp_part_kernel(
    const float* __restrict__ final_,
    const float* __restrict__ W1,   // [3840, 256]
    float* __restrict__ hpart)      // [32][8][256]
{
    const int b = blockIdx.x;
    const int c = blockIdx.y;
    const int tid = threadIdx.x;
    const int base = c * 480;

    __shared__ float fb[480];
    __shared__ float red[16][256];
    if (tid < 480) fb[tid] = final_[b * 3840 + base + tid];
    __syncthreads();

    const int g = tid >> 6;         // wave id, 16 waves
    const int q = tid & 63;         // column quad
    const float4* __restrict__ Wv = (const float4*)W1;   // [3840][64]
    float ax = 0.f, ay = 0.f, az = 0.f, aw = 0.f;
    const int l0 = g * 30;
    #pragma unroll 5
    for (int kk = 0; kk < 30; ++kk) {
        const float xv = fb[l0 + kk];
        const float4 w = Wv[(base + l0 + kk) * 64 + q];
        ax += xv * w.x; ay += xv * w.y; az += xv * w.z; aw += xv * w.w;
    }
    red[g][q * 4 + 0] = ax;
    red[g][q * 4 + 1] = ay;
    red[g][q * 4 + 2] = az;
    red[g][q * 4 + 3] = aw;
    __syncthreads();

    if (tid < 256) {
        float s = 0.f;
        #pragma unroll
        for (int g2 = 0; g2 < 16; ++g2) s += red[g2][tid];
        hpart[(b * 8 + c) * 256 + tid] = s;
    }
}

// MLP tail: combine K-partials, relu, [256x7] head, sigmoid. grid 32, 512 threads.
__global__ __launch_bounds__(512) void mlp_tail_kernel(
    const float* __restrict__ hpart,
    const float* __restrict__ b1,
    const float* __restrict__ W2,   // [256, 7]
    const float* __restrict__ b2,
    float* __restrict__ out)        // [32, 7]
{
    const int b = blockIdx.x;
    const int tid = threadIdx.x;

    __shared__ float hb[256];
    if (tid < 256) {
        float s = b1[tid];
        #pragma unroll
        for (int c = 0; c < 8; ++c) s += hpart[(b * 8 + c) * 256 + tid];
        hb[tid] = fmaxf(s, 0.f);
    }
    __syncthreads();

    const int w = tid >> 6;
    const int lane = tid & 63;
    if (w < 7) {
        float a = 0.f;
        #pragma unroll
        for (int c = lane; c < 256; c += 64)
            a += hb[c] * W2[c * 7 + w];
        #pragma unroll
        for (int off = 32; off > 0; off >>= 1)
            a += __shfl_down(a, off, 64);
        if (lane == 0)
            out[b * 7 + w] = 1.f / (1.f + __expf(-(a + b2[w])));
    }
}

extern "C" void kernel_launch(void* const* d_in, const int* in_sizes, int n_in,
                              void* d_out, int out_size, void* d_ws, size_t ws_size,
                              hipStream_t stream) {
    const float* sentence   = (const float*)d_in[0];
    const float* target     = (const float*)d_in[1];
    const float* other      = (const float*)d_in[2];
    const float* scene_desc = (const float*)d_in[3];
    const float* scene_sent = (const float*)d_in[4];
    const float* Ws         = (const float*)d_in[5];
    const float* bs         = (const float*)d_in[6];
    const float* W1         = (const float*)d_in[7];
    const float* b1         = (const float*)d_in[8];
    const float* W2         = (const float*)d_in[9];
    const float* b2         = (const float*)d_in[10];
    float* out = (float*)d_out;

    float* ctx    = (float*)d_ws;             // 32*1536 floats
    float* final_ = ctx + 32 * 1536;          // 32*3840 floats
    float* hpart  = final_ + 32 * 3840;       // 32*8*256 floats

    k1_small_attn_proj0<<<dim3(32, 25), 256, 0, stream>>>(sentence, target, other,
                                                          scene_desc, scene_sent,
                                                          Ws, bs, ctx, final_);
    k2_fused_attn_proj12<<<dim3(32, 38), 256, 0, stream>>>(sentence, ctx, Ws, bs, final_);
    mlp_part_kernel<<<dim3(32, 8), 1024, 0, stream>>>(final_, W1, hpart);
    mlp_tail_kernel<<<32, 512, 0, stream>>>(hpart, b1, W2, b2, out);
}